// Round 2
// baseline (106.431 us; speedup 1.0000x reference)
//
#include <hip/hip_runtime.h>

// Problem constants (match reference)
#define BB 2
#define NN 131072
#define MM 512
#define GG 20
#define VV (GG * GG * GG)   // 8000
#define NBLK 128            // min/accum blocks per batch
#define MAXSLOTS 1024       // <= B*M distinct sampled voxels per batch

// Workspace layout (no memsets -- K1 zeroes the Z-region itself):
//   0      partialMin : B * NBLK * 3 floats (3072 B, fully written by K1)
//   3072   minVals    : B * 3 floats        (24 B, written by K2)
//   3200   sflat      : B*M ints            (4096 B, written by K2)
//   8192   Z-region start:
//   8192   counters   : B ints (pad to 256)
//   8448   slotmap    : B*V ints  (64000 B)  0=unclaimed, else slot+1
//   72448  sums       : B*MAXSLOTS*10 floats (81920 B)
#define OFF_PARTIAL 0
#define OFF_MINV    3072
#define OFF_SFLAT   3200
#define OFF_Z       8192
#define OFF_CNT     8192
#define OFF_SLOTMAP 8448
#define OFF_SUMS    72448
#define ZWORDS      ((256 + 64000 + 81920) / 4)   // 36544 words

__device__ __forceinline__ int vox_coord(float p, float mn) {
    int i = (int)floorf((p - mn) * 2.0f);   // *2 == /0.5 (exact pow2)
    return min(max(i, 0), GG - 1);
}

// ---- K1: zero the Z-region + per-block coordinate-min partials ---------
__global__ void vox_k1(const float* __restrict__ x, char* __restrict__ ws) {
    const int b = blockIdx.y;
    const int tid = blockIdx.x * blockDim.x + threadIdx.x;      // 0..32767
    const int nthreads = gridDim.x * blockDim.x;                // 32768

    // zero slotmap + sums + counters (only batch-0 grid half does it once)
    if (b == 0) {
        int* z = (int*)(ws + OFF_Z);
        for (int i = tid; i < ZWORDS; i += nthreads) z[i] = 0;
    }

    // vectorized min: 3 float4 = 4 points per group
    const float4* xb = (const float4*)(x + (size_t)b * NN * 3);
    const int ngroups = (NN * 3) / 12;   // 32768
    float mx = 1e30f, my = 1e30f, mz = 1e30f;
    for (int g = tid; g < ngroups; g += nthreads) {
        float4 f0 = xb[3 * g + 0];
        float4 f1 = xb[3 * g + 1];
        float4 f2 = xb[3 * g + 2];
        mx = fminf(mx, fminf(fminf(f0.x, f0.w), fminf(f1.z, f2.y)));
        my = fminf(my, fminf(fminf(f0.y, f1.x), fminf(f1.w, f2.z)));
        mz = fminf(mz, fminf(fminf(f0.z, f1.y), fminf(f2.x, f2.w)));
    }
    // wave-64 reduction
    for (int off = 32; off > 0; off >>= 1) {
        mx = fminf(mx, __shfl_down(mx, off, 64));
        my = fminf(my, __shfl_down(my, off, 64));
        mz = fminf(mz, __shfl_down(mz, off, 64));
    }
    __shared__ float lmin[4][3];
    int wave = threadIdx.x >> 6;
    if ((threadIdx.x & 63) == 0) {
        lmin[wave][0] = mx; lmin[wave][1] = my; lmin[wave][2] = mz;
    }
    __syncthreads();
    if (threadIdx.x == 0) {
        float* pm = (float*)(ws + OFF_PARTIAL) + (b * NBLK + blockIdx.x) * 3;
        pm[0] = fminf(fminf(lmin[0][0], lmin[1][0]), fminf(lmin[2][0], lmin[3][0]));
        pm[1] = fminf(fminf(lmin[0][1], lmin[1][1]), fminf(lmin[2][1], lmin[3][1]));
        pm[2] = fminf(fminf(lmin[0][2], lmin[1][2]), fminf(lmin[2][2], lmin[3][2]));
    }
}

// ---- K2: reduce min partials, then mark sampled voxels (1 block) -------
__global__ void vox_k2(const float* __restrict__ x,
                       const int* __restrict__ sidx,
                       char* __restrict__ ws) {
    __shared__ float smin[BB][3];
    int t = threadIdx.x;                         // 0..1023
    if (t < BB * 3) {
        int b = t / 3, axis = t % 3;
        const float* pm = (const float*)(ws + OFF_PARTIAL);
        float m = 1e30f;
        for (int i = 0; i < NBLK; ++i) m = fminf(m, pm[(b * NBLK + i) * 3 + axis]);
        smin[b][axis] = m;
        ((float*)(ws + OFF_MINV))[b * 3 + axis] = m;
    }
    __syncthreads();

    int b = t >> 9;                              // t / M  (M=512)
    int pi = sidx[t];
    const float* p = x + ((size_t)b * NN + pi) * 3;
    int ix = vox_coord(p[0], smin[b][0]);
    int iy = vox_coord(p[1], smin[b][1]);
    int iz = vox_coord(p[2], smin[b][2]);
    int flat = (ix * GG + iy) * GG + iz;
    ((int*)(ws + OFF_SFLAT))[t] = flat;

    int* slotmap = (int*)(ws + OFF_SLOTMAP);
    int* counters = (int*)(ws + OFF_CNT);
    int old = atomicCAS(&slotmap[b * VV + flat], 0, -1);
    if (old == 0) {   // winner assigns a compact slot
        int s = atomicAdd(&counters[b], 1);
        slotmap[b * VV + flat] = s + 1;
    }
}

// ---- K3: accumulate sums for claimed voxels only -----------------------
// sums per (b,slot): [cnt, sx, sy, sz, sxx, sxy, sxz, syy, syz, szz]
__global__ void vox_k3(const float* __restrict__ x, char* __restrict__ ws) {
    const int b = blockIdx.y;
    const float* mv = (const float*)(ws + OFF_MINV) + b * 3;
    const float mnx = mv[0], mny = mv[1], mnz = mv[2];
    const int* slotmap = (const int*)(ws + OFF_SLOTMAP) + b * VV;
    float* sums = (float*)(ws + OFF_SUMS) + (size_t)b * MAXSLOTS * 10;

    const float4* xb = (const float4*)(x + (size_t)b * NN * 3);
    const int ngroups = (NN * 3) / 12;   // 32768
    const int tid = blockIdx.x * blockDim.x + threadIdx.x;
    const int nthreads = gridDim.x * blockDim.x;

    for (int g = tid; g < ngroups; g += nthreads) {
        float4 f0 = xb[3 * g + 0];
        float4 f1 = xb[3 * g + 1];
        float4 f2 = xb[3 * g + 2];
        float px[4] = {f0.x, f0.w, f1.z, f2.y};
        float py[4] = {f0.y, f1.x, f1.w, f2.z};
        float pz[4] = {f0.z, f1.y, f2.x, f2.w};
#pragma unroll
        for (int k = 0; k < 4; ++k) {
            int ix = vox_coord(px[k], mnx);
            int iy = vox_coord(py[k], mny);
            int iz = vox_coord(pz[k], mnz);
            int slot = slotmap[(ix * GG + iy) * GG + iz];
            if (slot > 0) {
                float* s = sums + (size_t)(slot - 1) * 10;
                atomicAdd(s + 0, 1.0f);
                atomicAdd(s + 1, px[k]);
                atomicAdd(s + 2, py[k]);
                atomicAdd(s + 3, pz[k]);
                atomicAdd(s + 4, px[k] * px[k]);
                atomicAdd(s + 5, px[k] * py[k]);
                atomicAdd(s + 6, px[k] * pz[k]);
                atomicAdd(s + 7, py[k] * py[k]);
                atomicAdd(s + 8, py[k] * pz[k]);
                atomicAdd(s + 9, pz[k] * pz[k]);
            }
        }
    }
}

// ---- K4: finalize mean/cov at sampled voxels ---------------------------
__global__ void vox_k4(const char* __restrict__ ws, float* __restrict__ out) {
    int t = blockIdx.x * blockDim.x + threadIdx.x;
    if (t >= BB * MM) return;
    int b = t >> 9;
    int flat = ((const int*)(ws + OFF_SFLAT))[t];
    int slot = ((const int*)(ws + OFF_SLOTMAP))[b * VV + flat] - 1;
    const float* s = (const float*)(ws + OFF_SUMS) + ((size_t)b * MAXSLOTS + slot) * 10;
    float cnt = s[0];
    float inv = 1.0f / fmaxf(cnt, 1.0f);
    float mx = s[1] * inv, my = s[2] * inv, mz = s[3] * inv;
    float cxx = s[4] * inv - mx * mx;
    float cxy = s[5] * inv - mx * my;
    float cxz = s[6] * inv - mx * mz;
    float cyy = s[7] * inv - my * my;
    float cyz = s[8] * inv - my * mz;
    float czz = s[9] * inv - mz * mz;
    float* o = out + (size_t)t * 12;
    o[0] = mx;  o[1] = my;  o[2] = mz;
    o[3] = cxx; o[4] = cxy; o[5] = cxz;
    o[6] = cxy; o[7] = cyy; o[8] = cyz;
    o[9] = cxz; o[10] = cyz; o[11] = czz;
}

extern "C" void kernel_launch(void* const* d_in, const int* in_sizes, int n_in,
                              void* d_out, int out_size, void* d_ws, size_t ws_size,
                              hipStream_t stream) {
    const float* x = (const float*)d_in[0];   // (B, N, 3) fp32
    const int* sidx = (const int*)d_in[1];    // (B, M) int32
    float* out = (float*)d_out;               // (B, M, 12) fp32
    char* ws = (char*)d_ws;

    vox_k1<<<dim3(NBLK, BB), 256, 0, stream>>>(x, ws);
    vox_k2<<<1, BB * MM, 0, stream>>>(x, sidx, ws);
    vox_k3<<<dim3(NBLK, BB), 256, 0, stream>>>(x, ws);
    vox_k4<<<(BB * MM + 255) / 256, 256, 0, stream>>>(ws, out);
}